// Round 12
// baseline (207.368 us; speedup 1.0000x reference)
//
#include <hip/hip_runtime.h>
#include <hip/hip_bf16.h>

#define NP 300
#define PM 320
#define HID 4069
#define KD 25088
#define FW 37
#define FC 512

// ---- gemm1 geometry: BM=320, BN1=64, BK1=32, KSPLIT1=8; grid 512; 48 KiB LDS -> 2 blocks/CU ----
#define BK1 32
#define BN1 64
#define KSPLIT1 8
#define KC1 (KD/KSPLIT1)        // 3136
#define NSTEP1 (KC1/BK1)        // 98 (even; 2-step epilogue peeled)
#define A1BYTES (PM*BK1*2)      // 20480
#define B1BYTES (BN1*BK1*2)     // 4096
#define BUF1 (A1BYTES + B1BYTES) // 24576 (2 bufs = 48 KiB LDS)

// ---- gemm2 geometry: BN=64, BK=64, split-K over 4096-padded K ----
#define BK 64
#define BN 64
#define ABYTES (PM*BK*2)        // 40960
#define BUFBYTES (ABYTES + BN*BK*2)  // 49152
#define K2PAD 4096
#define KSL 32
#define KC2 (K2PAD/KSL)         // 128
#define NSTEP2 (KC2/BK)         // 2

typedef __attribute__((ext_vector_type(4))) float f32x4;
typedef __attribute__((ext_vector_type(8))) short bf16x8;

__device__ inline unsigned short f2bf(float x) {
  __hip_bfloat16 h = __float2bfloat16(x);
  return *reinterpret_cast<unsigned short*>(&h);
}

// ---------------- ROI pool: (37,37,512) + (300,4) -> bf16 [320][25088] ----------------
__global__ void roi_pool_k(const float* __restrict__ fmap,
                           const float* __restrict__ props,
                           unsigned short* __restrict__ pooled) {
  int p = blockIdx.x;
  int t = threadIdx.x;
  if (p >= NP) {
    unsigned int* row = (unsigned int*)(pooled + (size_t)p * KD);
    for (int i = t; i < KD/2; i += 256) row[i] = 0u;
    return;
  }
  float y1 = props[p*4+0], x1 = props[p*4+1], y2 = props[p*4+2], x2 = props[p*4+3];
  int c = t * 2;
  for (int py = 0; py < 7; ++py) {
    float ty = (float)py * (1.0f/6.0f);
    float ys = (y1 + ty * (y2 - y1)) * 36.0f;
    ys = fminf(fmaxf(ys, 0.0f), 36.0f);
    int y0 = (int)floorf(ys);
    y0 = min(max(y0, 0), 35);
    float yf = ys - (float)y0;
    for (int px = 0; px < 7; ++px) {
      float tx = (float)px * (1.0f/6.0f);
      float xs = (x1 + tx * (x2 - x1)) * 36.0f;
      xs = fminf(fmaxf(xs, 0.0f), 36.0f);
      int x0 = (int)floorf(xs);
      x0 = min(max(x0, 0), 35);
      float xf = xs - (float)x0;
      const float* base = fmap + ((size_t)y0 * FW + x0) * FC + c;
      float2 tl = *(const float2*)(base);
      float2 tr = *(const float2*)(base + FC);
      float2 bl = *(const float2*)(base + FW*FC);
      float2 br = *(const float2*)(base + FW*FC + FC);
      float tpx = tl.x*(1.f-xf) + tr.x*xf;
      float tpy = tl.y*(1.f-xf) + tr.y*xf;
      float btx = bl.x*(1.f-xf) + br.x*xf;
      float bty = bl.y*(1.f-xf) + br.y*xf;
      float vx = tpx*(1.f-yf) + btx*yf;
      float vy = tpy*(1.f-yf) + bty*yf;
      unsigned int packed = (unsigned int)f2bf(vx) | ((unsigned int)f2bf(vy) << 16);
      *(unsigned int*)(pooled + (size_t)p*KD + ((py*7+px)*FC + c)) = packed;
    }
  }
}

// swizzle helper: 64B LDS rows, 4x16B slots; slot ^= f(row) gives conflict-light frag reads
#define FSWZ(x) (((x) ^ ((x) >> 2)) & 3)

// ---------------- GEMM1: A[320][25088]bf16 x W1[25088][4069]f32 -> partials f32 ----------------
// R10 probe: latency-bound (HBM 21%, Mfma 20%, Occ 24%). R11 bug: LDS shrunk but grid stayed 256
// (no 2nd block existed). Fix: grid 512 = 64 ntiles (BN=64) x 8 kc -> TRUE 2 blocks/CU;
// W1 still read exactly once (disjoint column panels). kc=bid&7 pins A-chunk to one XCD's L2.
__global__ __launch_bounds__(512, 4)
void gemm1_k(const unsigned short* __restrict__ A,
             const float* __restrict__ W1,
             float* __restrict__ part) {
  __shared__ char lds[2*BUF1];   // 48 KiB
  const int t = threadIdx.x;
  const int wave = t >> 6;
  const int lane = t & 63;
  const int bid = blockIdx.x;       // 0..511
  const int kc = bid & 7;           // XCD-pinned A-chunk (2 MB, L2-resident, shared by 64 blocks)
  const int ntile = bid >> 3;       // 0..63
  const int n0 = ntile * BN1;
  const int kstart0 = kc * KC1;

  // B load geometry: thread -> (1 col, 4 k's); 64 lanes = 256B burst per k-row
  const int bcol = t & 63;
  const int bkq  = t >> 6;          // 0..7 -> k base bkq*4
  const int ngc  = min(n0 + bcol, HID-1);
  const int bwoff = A1BYTES + bcol*64 + ((((bkq >> 1) ^ FSWZ(bcol)) << 4) | ((bkq & 1) << 3));

  const int wm = wave >> 1;   // 0..3 -> 80 rows
  const int wn = wave & 1;    // 0..1 -> 32 cols

  int aoff[5], boff[2];
  #pragma unroll
  for (int fm = 0; fm < 5; ++fm) {
    int row = wm*80 + fm*16 + (lane & 15);
    aoff[fm] = row*64 + (((lane >> 4) ^ FSWZ(row)) << 4);
  }
  #pragma unroll
  for (int fn = 0; fn < 2; ++fn) {
    int col = wn*32 + fn*16 + (lane & 15);
    boff[fn] = A1BYTES + col*64 + (((lane >> 4) ^ FSWZ(col)) << 4);
  }

  f32x4 acc[5][2];
  #pragma unroll
  for (int fm=0; fm<5; ++fm)
    #pragma unroll
    for (int fn=0; fn<2; ++fn)
      acc[fm][fn] = (f32x4){0.f,0.f,0.f,0.f};

  // stage 20 KB A tile: per wave 2 x (64x16B) + 2 x (64x4B) = 4 VMEM ops
  // linear LDS dest + inverse-swizzled global source (rule #21) -- verified in R11 (refcheck'd)
  auto stageA = [&](int s, int buf) {
    const int kstart = kstart0 + s*BK1;
    char* dstbase = lds + buf*BUF1;
    #pragma unroll
    for (int i = 0; i < 2; ++i) {
      int o = (wave*2 + i)*1024 + lane*16;
      int row = o >> 6;
      int kb = (((((o >> 4) & 3) ^ FSWZ(row)) << 4)) | (o & 15);
      const char* g = (const char*)A + (size_t)row*(KD*2) + (size_t)kstart*2 + kb;
      __builtin_amdgcn_global_load_lds(
          (const __attribute__((address_space(1))) unsigned int*)g,
          (__attribute__((address_space(3))) unsigned int*)(dstbase + o),
          16, 0, 0);
    }
    #pragma unroll
    for (int j = 0; j < 2; ++j) {
      int o = 16384 + (wave*2 + j)*256 + lane*4;
      int row = o >> 6;
      int kb = (((((o >> 4) & 3) ^ FSWZ(row)) << 4)) | (o & 15);
      const char* g = (const char*)A + (size_t)row*(KD*2) + (size_t)kstart*2 + kb;
      __builtin_amdgcn_global_load_lds(
          (const __attribute__((address_space(1))) unsigned int*)g,
          (__attribute__((address_space(3))) unsigned int*)(dstbase + o),
          4, 0, 0);
    }
  };
  auto compute = [&](int buf) {
    const char* base = lds + buf*BUF1;
    bf16x8 af[5], bfr[2];
    #pragma unroll
    for (int fm = 0; fm < 5; ++fm) af[fm] = *(const bf16x8*)(base + aoff[fm]);
    #pragma unroll
    for (int fn = 0; fn < 2; ++fn) bfr[fn] = *(const bf16x8*)(base + boff[fn]);
    #pragma unroll
    for (int fm = 0; fm < 5; ++fm)
      #pragma unroll
      for (int fn = 0; fn < 2; ++fn)
        acc[fm][fn] = __builtin_amdgcn_mfma_f32_16x16x32_bf16(af[fm], bfr[fn], acc[fm][fn], 0, 0, 0);
  };

#define LOADB(s, bv) do {                                                     \
    const float* _src = W1 + (size_t)((kstart0 + (s)*BK1) + bkq*4) * HID + ngc; \
    _Pragma("unroll")                                                         \
    for (int _i = 0; _i < 4; ++_i) bv[_i] = _src[(size_t)_i * HID];           \
  } while (0)

#define WRITEB(bv, buf) do {                                                  \
    unsigned int _lo = (unsigned int)f2bf(bv[0]) | ((unsigned int)f2bf(bv[1]) << 16); \
    unsigned int _hi = (unsigned int)f2bf(bv[2]) | ((unsigned int)f2bf(bv[3]) << 16); \
    *(uint2*)(lds + (buf)*BUF1 + bwoff) = make_uint2(_lo, _hi);               \
  } while (0)

  float bvA[4], bvB[4];

  // prologue: tile 0 -> buf0; preload B(1)
  stageA(0, 0);
  LOADB(0, bvA);
  WRITEB(bvA, 0);           // implicit wait retires A(0)+B(0) (FIFO)
  LOADB(1, bvA);
  asm volatile("s_waitcnt vmcnt(4) lgkmcnt(0)" ::: "memory");
  __builtin_amdgcn_s_barrier();
  __builtin_amdgcn_sched_barrier(0);

  // STEP(s): stage A(s+1) [4 ops], load B(s+2) [4 ops], write B(s+1), compute(s).
  // Barrier vmcnt(4): retires the 4 A-staging ops, keeps 4 B(s+2) loads in flight.
#define STEP(s, bvC, bvO) do {                                        \
    stageA((s)+1, ((s)&1)^1);                                         \
    LOADB((s)+2, bvO);                                                \
    WRITEB(bvC, ((s)&1)^1);                                           \
    compute((s)&1);                                                   \
    asm volatile("s_waitcnt vmcnt(4) lgkmcnt(0)" ::: "memory");       \
    __builtin_amdgcn_s_barrier();                                     \
    __builtin_amdgcn_sched_barrier(0);                                \
  } while (0)

  for (int s = 0; s + 3 < NSTEP1; s += 2) {  // s = 0,2,...,94 -> steps 0..95
    STEP(s, bvA, bvB);
    STEP(s + 1, bvB, bvA);
  }
  { // s = 96: stage A(97), write B(97) (in bvA), no more B loads
    stageA(NSTEP1 - 1, 1);
    WRITEB(bvA, 1);
    compute(0);
    asm volatile("s_waitcnt vmcnt(0) lgkmcnt(0)" ::: "memory");
    __builtin_amdgcn_s_barrier();
    __builtin_amdgcn_sched_barrier(0);
  }
  compute(1);                                // s = 97

#undef STEP
#undef LOADB
#undef WRITEB

  float* dst = part + (size_t)kc * NP * HID;
  #pragma unroll
  for (int fm = 0; fm < 5; ++fm) {
    #pragma unroll
    for (int fn = 0; fn < 2; ++fn) {
      int ncol = n0 + wn*32 + fn*16 + (lane & 15);
      #pragma unroll
      for (int j = 0; j < 4; ++j) {
        int m = wm*80 + fm*16 + ((lane >> 4) * 4) + j;
        if (m < NP && ncol < HID)
          dst[(size_t)m * HID + ncol] = acc[fm][fn][j];
      }
    }
  }
}

// ---------------- reduce 8 partials + bias + relu -> h bf16 [320][4096] ----------------
__global__ void reduce_k(const float* __restrict__ part,
                         const float* __restrict__ b1,
                         unsigned short* __restrict__ hb) {
  int n = blockIdx.x * 256 + threadIdx.x;
  int p = blockIdx.y;
  if (n >= K2PAD) return;
  float v = 0.0f;
  if (n < HID) {
    size_t i = (size_t)p * HID + n;
    const size_t S = (size_t)NP * HID;
    float s0 = 0.f;
    #pragma unroll
    for (int k = 0; k < KSPLIT1; ++k) s0 += part[i + (size_t)k*S];
    v = fmaxf(s0 + b1[n], 0.0f);
  }
  hb[(size_t)p * K2PAD + n] = f2bf(v);
}

// ---------------- GEMM2 (MFMA split-K): hb[320][4096] x [Wc|Wr|0][4096][128] -> part2 ----------------
__global__ __launch_bounds__(512, 1)
void gemm2_k(const unsigned short* __restrict__ hb,
             const float* __restrict__ Wc,
             const float* __restrict__ Wr,
             float* __restrict__ part2) {
  __shared__ char lds[2*BUFBYTES];
  const int t = threadIdx.x;
  const int wave = t >> 6;
  const int lane = t & 63;
  const int ntile = blockIdx.x;
  const int kc = blockIdx.y;
  const int n0 = ntile * BN;
  const int kstart0 = kc * KC2;

  const int bn_l = t & 63;
  const int bk8  = (t >> 6) * 8;
  const int jn   = n0 + bn_l;
  const float* bsrc; int bst;
  if (jn < 21)        { bsrc = Wc + jn;        bst = 21; }
  else if (jn < 101)  { bsrc = Wr + (jn - 21); bst = 80; }
  else                { bsrc = nullptr;        bst = 0;  }
  const int bwoff = ABYTES + bn_l*128 + ((bk8*2) ^ ((bn_l & 7) << 4));

  const int wm = wave >> 1;
  const int wn = wave & 1;

  int aoff[5][2], boff[2][2];
  #pragma unroll
  for (int fm = 0; fm < 5; ++fm) {
    int row = wm*80 + fm*16 + (lane & 15);
    #pragma unroll
    for (int h = 0; h < 2; ++h) {
      int kb = (h << 6) | ((lane >> 4) << 4);
      aoff[fm][h] = row*128 + (kb ^ ((row & 7) << 4));
    }
  }
  #pragma unroll
  for (int fn = 0; fn < 2; ++fn) {
    int col = wn*32 + fn*16 + (lane & 15);
    #pragma unroll
    for (int h = 0; h < 2; ++h) {
      int kb = (h << 6) | ((lane >> 4) << 4);
      boff[fn][h] = ABYTES + col*128 + (kb ^ ((col & 7) << 4));
    }
  }

  f32x4 acc[5][2];
  #pragma unroll
  for (int fm=0; fm<5; ++fm)
    #pragma unroll
    for (int fn=0; fn<2; ++fn)
      acc[fm][fn] = (f32x4){0.f,0.f,0.f,0.f};

  auto stageA = [&](int s, int buf) {
    const int kstart = kstart0 + s*BK;
    char* dstbase = lds + buf*BUFBYTES;
    #pragma unroll
    for (int i = 0; i < 5; ++i) {
      int chunk = wave*5 + i;
      int o = chunk*1024 + lane*16;
      int row = o >> 7;
      int kb = (o & 127) ^ ((row & 7) << 4);
      const char* g = (const char*)hb + (size_t)row*(K2PAD*2) + (size_t)kstart*2 + kb;
      __builtin_amdgcn_global_load_lds(
          (const __attribute__((address_space(1))) unsigned int*)g,
          (__attribute__((address_space(3))) unsigned int*)(dstbase + chunk*1024),
          16, 0, 0);
    }
  };
  auto loadB = [&](int s, float* bv) {
    const int kstart = kstart0 + s*BK;
    #pragma unroll
    for (int i = 0; i < 8; ++i) {
      int k = kstart + bk8 + i;
      bv[i] = (bsrc && k < HID) ? bsrc[(size_t)k * bst] : 0.0f;
    }
  };
  auto writeB = [&](const float* bv, int buf) {
    bf16x8 bb;
    #pragma unroll
    for (int i = 0; i < 8; ++i) bb[i] = (short)f2bf(bv[i]);
    *(bf16x8*)(lds + buf*BUFBYTES + bwoff) = bb;
  };
  auto compute = [&](int buf) {
    const char* base = lds + buf*BUFBYTES;
    #pragma unroll
    for (int h = 0; h < 2; ++h) {
      bf16x8 af[5], bfr[2];
      #pragma unroll
      for (int fm = 0; fm < 5; ++fm) af[fm] = *(const bf16x8*)(base + aoff[fm][h]);
      #pragma unroll
      for (int fn = 0; fn < 2; ++fn) bfr[fn] = *(const bf16x8*)(base + boff[fn][h]);
      #pragma unroll
      for (int fm = 0; fm < 5; ++fm)
        #pragma unroll
        for (int fn = 0; fn < 2; ++fn)
          acc[fm][fn] = __builtin_amdgcn_mfma_f32_16x16x32_bf16(af[fm], bfr[fn], acc[fm][fn], 0, 0, 0);
    }
  };

  {
    float bv[8];
    loadB(0, bv);
    stageA(0, 0);
    writeB(bv, 0);
  }
  __syncthreads();

  for (int s = 0; s < NSTEP2; ++s) {
    int cur = s & 1;
    float bv[8];
    if (s + 1 < NSTEP2) {
      loadB(s+1, bv);
      stageA(s+1, cur^1);
    }
    compute(cur);
    if (s + 1 < NSTEP2) {
      writeB(bv, cur^1);
    }
    __syncthreads();
  }

  float* dst = part2 + (size_t)kc * PM * 128;
  #pragma unroll
  for (int fm = 0; fm < 5; ++fm) {
    #pragma unroll
    for (int fn = 0; fn < 2; ++fn) {
      int ncol = n0 + wn*32 + fn*16 + (lane & 15);
      #pragma unroll
      for (int j = 0; j < 4; ++j) {
        int m = wm*80 + fm*16 + ((lane >> 4) * 4) + j;
        dst[(size_t)m * 128 + ncol] = acc[fm][fn][j];
      }
    }
  }
}

// ---------------- reduce2: sum K-slices + bias -> out ----------------
__global__ void reduce2_k(const float* __restrict__ part2,
                          const float* __restrict__ bc,
                          const float* __restrict__ br,
                          float* __restrict__ out) {
  int p = blockIdx.x;
  int j = threadIdx.x;
  if (j >= 101) return;
  float s = 0.0f;
  #pragma unroll 8
  for (int k = 0; k < KSL; ++k)
    s += part2[(size_t)k * PM * 128 + (size_t)p * 128 + j];
  if (j < 21) out[(size_t)p*21 + j] = s + bc[j];
  else        out[6300 + (size_t)p*80 + (j-21)] = s + br[j-21];
}

extern "C" void kernel_launch(void* const* d_in, const int* in_sizes, int n_in,
                              void* d_out, int out_size, void* d_ws, size_t ws_size,
                              hipStream_t stream) {
  const float* fmap  = (const float*)d_in[0];
  const float* props = (const float*)d_in[1];
  const float* W1    = (const float*)d_in[2];
  const float* b1    = (const float*)d_in[3];
  const float* Wc    = (const float*)d_in[4];
  const float* bc    = (const float*)d_in[5];
  const float* Wr    = (const float*)d_in[6];
  const float* br    = (const float*)d_in[7];
  float* out = (float*)d_out;
  char* ws = (char*)d_ws;

  unsigned short* pooled = (unsigned short*)ws;                     // 16,056,320 B
  float* part = (float*)(ws + 16056320);                            // 8*300*4069*4 = 39,062,400 B
  unsigned short* hb = (unsigned short*)(ws + 16056320 + 39062400); //  2,621,440 B
  float* part2 = (float*)(ws + 16056320 + 39062400 + 2621440);      //  5,242,880 B

  roi_pool_k<<<PM, 256, 0, stream>>>(fmap, props, pooled);
  gemm1_k<<<512, 512, 0, stream>>>(pooled, W1, part);
  reduce_k<<<dim3(K2PAD/256, NP), 256, 0, stream>>>(part, b1, hb);
  gemm2_k<<<dim3(2, KSL), 512, 0, stream>>>(hb, Wc, Wr, part2);
  reduce2_k<<<NP, 128, 0, stream>>>(part2, bc, br, out);
}

// Round 13
// 151.371 us; speedup vs baseline: 1.3699x; 1.3699x over previous
//
#include <hip/hip_runtime.h>
#include <hip/hip_bf16.h>

#define NP 300
#define PM 320
#define HID 4069
#define KD 25088
#define FW 37
#define FC 512

#define BK 64

// ---- gemm1 geometry: R4 verbatim (BM=320, BN1=128, BK=64, KSPLIT1=8, grid 256) ----
// Change vs R4: B prefetch depth 3 (regs bv0/1/2), A triple-buffered -> 32 B-loads
// stay in flight across every barrier (64 KB/CU vs R4's 32 KB).
#define BN1 128
#define KSPLIT1 8
#define KC1 (KD/KSPLIT1)        // 3136
#define NSTEP1 (KC1/BK)         // 49
#define A1BYTES (PM*BK*2)       // 40960
#define B1BYTES (BN1*BK*2)      // 16384
#define BOFF0 (3*A1BYTES)       // B region after 3 A bufs; total LDS = 122880+32768 = 155648 (152K)

// ---- gemm2 geometry: BN=64, split-K over 4096-padded K ----
#define BN 64
#define ABYTES (PM*BK*2)        // 40960
#define BUFBYTES (ABYTES + BN*BK*2)  // 49152
#define K2PAD 4096
#define KSL 32
#define KC2 (K2PAD/KSL)         // 128
#define NSTEP2 (KC2/BK)         // 2

typedef __attribute__((ext_vector_type(4))) float f32x4;
typedef __attribute__((ext_vector_type(8))) short bf16x8;

__device__ inline unsigned short f2bf(float x) {
  __hip_bfloat16 h = __float2bfloat16(x);
  return *reinterpret_cast<unsigned short*>(&h);
}

// ---------------- ROI pool: (37,37,512) + (300,4) -> bf16 [320][25088] ----------------
__global__ void roi_pool_k(const float* __restrict__ fmap,
                           const float* __restrict__ props,
                           unsigned short* __restrict__ pooled) {
  int p = blockIdx.x;
  int t = threadIdx.x;
  if (p >= NP) {
    unsigned int* row = (unsigned int*)(pooled + (size_t)p * KD);
    for (int i = t; i < KD/2; i += 256) row[i] = 0u;
    return;
  }
  float y1 = props[p*4+0], x1 = props[p*4+1], y2 = props[p*4+2], x2 = props[p*4+3];
  int c = t * 2;
  for (int py = 0; py < 7; ++py) {
    float ty = (float)py * (1.0f/6.0f);
    float ys = (y1 + ty * (y2 - y1)) * 36.0f;
    ys = fminf(fmaxf(ys, 0.0f), 36.0f);
    int y0 = (int)floorf(ys);
    y0 = min(max(y0, 0), 35);
    float yf = ys - (float)y0;
    for (int px = 0; px < 7; ++px) {
      float tx = (float)px * (1.0f/6.0f);
      float xs = (x1 + tx * (x2 - x1)) * 36.0f;
      xs = fminf(fmaxf(xs, 0.0f), 36.0f);
      int x0 = (int)floorf(xs);
      x0 = min(max(x0, 0), 35);
      float xf = xs - (float)x0;
      const float* base = fmap + ((size_t)y0 * FW + x0) * FC + c;
      float2 tl = *(const float2*)(base);
      float2 tr = *(const float2*)(base + FC);
      float2 bl = *(const float2*)(base + FW*FC);
      float2 br = *(const float2*)(base + FW*FC + FC);
      float tpx = tl.x*(1.f-xf) + tr.x*xf;
      float tpy = tl.y*(1.f-xf) + tr.y*xf;
      float btx = bl.x*(1.f-xf) + br.x*xf;
      float bty = bl.y*(1.f-xf) + br.y*xf;
      float vx = tpx*(1.f-yf) + btx*yf;
      float vy = tpy*(1.f-yf) + bty*yf;
      unsigned int packed = (unsigned int)f2bf(vx) | ((unsigned int)f2bf(vy) << 16);
      *(unsigned int*)(pooled + (size_t)p*KD + ((py*7+px)*FC + c)) = packed;
    }
  }
}

// ---------------- GEMM1: A[320][25088]bf16 x W1[25088][4069]f32 -> partials f32 ----------------
__global__ __launch_bounds__(512, 2)
void gemm1_k(const unsigned short* __restrict__ A,
             const float* __restrict__ W1,
             float* __restrict__ part) {
  __shared__ char lds[3*A1BYTES + 2*B1BYTES];   // 152 KiB
  const int t = threadIdx.x;
  const int wave = t >> 6;
  const int lane = t & 63;
  const int bid = blockIdx.x;       // 0..255
  const int kc = bid & 7;           // XCD-pinned A-chunk (2 MB L2-resident)
  const int ntile = bid >> 3;       // 0..31
  const int n0 = ntile * BN1;
  const int kstart0 = kc * KC1;

  // B load geometry: thread -> (col, 16 k's) -- R4 verbatim
  const int bcol = t & 127;
  const int bkg  = t >> 7;          // 0..3 -> k base bkg*16
  const int ngc  = min(n0 + bcol, HID-1);
  const int c7m  = (bcol & 7) << 4;
  const int bw0 = bcol*128 + ((bkg*32)      ^ c7m);   // relative to B region
  const int bw1 = bcol*128 + ((bkg*32 + 16) ^ c7m);

  const int wm = wave >> 1;   // 0..3 -> 80 rows
  const int wn = wave & 1;    // 0..1 -> 64 cols

  int aoff[5][2], boff[4][2];
  #pragma unroll
  for (int fm = 0; fm < 5; ++fm) {
    int row = wm*80 + fm*16 + (lane & 15);
    #pragma unroll
    for (int h = 0; h < 2; ++h) {
      int kb = (h << 6) | ((lane >> 4) << 4);
      aoff[fm][h] = row*128 + (kb ^ ((row & 7) << 4));
    }
  }
  #pragma unroll
  for (int fn = 0; fn < 4; ++fn) {
    int col = wn*64 + fn*16 + (lane & 15);
    #pragma unroll
    for (int h = 0; h < 2; ++h) {
      int kb = (h << 6) | ((lane >> 4) << 4);
      boff[fn][h] = col*128 + (kb ^ ((col & 7) << 4));   // relative to B region
    }
  }

  f32x4 acc[5][4];
  #pragma unroll
  for (int fm=0; fm<5; ++fm)
    #pragma unroll
    for (int fn=0; fn<4; ++fn)
      acc[fm][fn] = (f32x4){0.f,0.f,0.f,0.f};

  auto stageA = [&](int s, int ab) {   // R4 verbatim, dest = abuf[ab]
    const int kstart = kstart0 + s*BK;
    char* dstbase = lds + ab*A1BYTES;
    #pragma unroll
    for (int i = 0; i < 5; ++i) {
      int chunk = wave*5 + i;
      int o = chunk*1024 + lane*16;
      int row = o >> 7;
      int kb = (o & 127) ^ ((row & 7) << 4);
      const char* g = (const char*)A + (size_t)row*(KD*2) + (size_t)kstart*2 + kb;
      __builtin_amdgcn_global_load_lds(
          (const __attribute__((address_space(1))) unsigned int*)g,
          (__attribute__((address_space(3))) unsigned int*)(dstbase + chunk*1024),
          16, 0, 0);
    }
  };
  auto compute = [&](int ab, int bb) {
    const char* abase = lds + ab*A1BYTES;
    const char* bbase = lds + BOFF0 + bb*B1BYTES;
    #pragma unroll
    for (int h = 0; h < 2; ++h) {
      bf16x8 af[5], bfr[4];
      #pragma unroll
      for (int fm = 0; fm < 5; ++fm) af[fm] = *(const bf16x8*)(abase + aoff[fm][h]);
      #pragma unroll
      for (int fn = 0; fn < 4; ++fn) bfr[fn] = *(const bf16x8*)(bbase + boff[fn][h]);
      #pragma unroll
      for (int fm = 0; fm < 5; ++fm)
        #pragma unroll
        for (int fn = 0; fn < 4; ++fn)
          acc[fm][fn] = __builtin_amdgcn_mfma_f32_16x16x32_bf16(af[fm], bfr[fn], acc[fm][fn], 0, 0, 0);
    }
  };

#define LOADB(s, bv) do {                                                     \
    const float* _src = W1 + (size_t)((kstart0 + (s)*BK) + bkg*16) * HID + ngc; \
    _Pragma("unroll")                                                         \
    for (int _i = 0; _i < 16; ++_i) bv[_i] = _src[(size_t)_i * HID];          \
  } while (0)

#define WRITEB(bv, bb) do {                                                   \
    bf16x8 _b0, _b1;                                                          \
    _Pragma("unroll")                                                         \
    for (int _i = 0; _i < 8; ++_i) { _b0[_i] = (short)f2bf(bv[_i]);           \
                                     _b1[_i] = (short)f2bf(bv[8+_i]); }       \
    *(bf16x8*)(lds + BOFF0 + (bb)*B1BYTES + bw0) = _b0;                       \
    *(bf16x8*)(lds + BOFF0 + (bb)*B1BYTES + bw1) = _b1;                       \
  } while (0)

  float bv0[16], bv1[16], bv2[16];

  // ---- prologue ----
  // FIFO: B(0)16 | A(0)5 | A(1)5 | B(1)16 | B(2)16
  LOADB(0, bv0);
  stageA(0, 0);
  stageA(1, 1);
  LOADB(1, bv1);
  LOADB(2, bv2);
  WRITEB(bv0, 0);   // implicit wait retires B(0) only (oldest 16)
  asm volatile("s_waitcnt vmcnt(37) lgkmcnt(0)" ::: "memory");   // retire A(0)
  __builtin_amdgcn_s_barrier();
  __builtin_amdgcn_sched_barrier(0);

  // STEPX(s): stage A(s+2)->abuf AS, load B(s+3)->bvO, compute(s) from (AC,BB),
  // write B(s+1) from bvW -> bbuf BW. Barrier vmcnt(37): retires A(s+1) [issued
  // step s-1], keeps B(s+2)16 + A(s+2)5 + B(s+3)16 = 37 in flight (64 KB B/CU).
#define STEPX(s, AC, AS, BB, BW, bvW, bvO) do {                       \
    stageA((s)+2, AS);                                                \
    LOADB((s)+3, bvO);                                                \
    compute(AC, BB);                                                  \
    WRITEB(bvW, BW);                                                  \
    asm volatile("s_waitcnt vmcnt(37) lgkmcnt(0)" ::: "memory");      \
    __builtin_amdgcn_s_barrier();                                     \
    __builtin_amdgcn_sched_barrier(0);                                \
  } while (0)

  // main loop: steps 0..41 (s multiple of 6 -> s%3==0, s%2==0; all indices static)
  for (int s = 0; s < 42; s += 6) {
    STEPX(s+0, 0, 2, 0, 1, bv1, bv0);
    STEPX(s+1, 1, 0, 1, 0, bv2, bv1);
    STEPX(s+2, 2, 1, 0, 1, bv0, bv2);
    STEPX(s+3, 0, 2, 1, 0, bv1, bv0);
    STEPX(s+4, 1, 0, 0, 1, bv2, bv1);
    STEPX(s+5, 2, 1, 1, 0, bv0, bv2);
  }
  // peeled tail: steps 42..48 (NSTEP1 = 49)
  STEPX(42, 0, 2, 0, 1, bv1, bv0);   // loads B(45)
  STEPX(43, 1, 0, 1, 0, bv2, bv1);   // loads B(46)
  STEPX(44, 2, 1, 0, 1, bv0, bv2);   // loads B(47)
  STEPX(45, 0, 2, 1, 0, bv1, bv0);   // loads B(48) -> bv0
  { // s = 46: stage A(48), no more B loads
    stageA(48, 0);
    compute(1, 0);
    WRITEB(bv2, 1);                  // B(47)
    asm volatile("s_waitcnt vmcnt(21) lgkmcnt(0)" ::: "memory");   // retire A(47)
    __builtin_amdgcn_s_barrier();
    __builtin_amdgcn_sched_barrier(0);
  }
  { // s = 47: last write
    compute(2, 1);
    WRITEB(bv0, 0);                  // B(48); implicit wait retires B(48)
    asm volatile("s_waitcnt vmcnt(0) lgkmcnt(0)" ::: "memory");    // drain A(48)
    __builtin_amdgcn_s_barrier();
    __builtin_amdgcn_sched_barrier(0);
  }
  compute(0, 0);                     // s = 48

#undef STEPX
#undef LOADB
#undef WRITEB

  float* dst = part + (size_t)kc * NP * HID;
  #pragma unroll
  for (int fm = 0; fm < 5; ++fm) {
    #pragma unroll
    for (int fn = 0; fn < 4; ++fn) {
      int ncol = n0 + wn*64 + fn*16 + (lane & 15);
      #pragma unroll
      for (int j = 0; j < 4; ++j) {
        int m = wm*80 + fm*16 + ((lane >> 4) * 4) + j;
        if (m < NP && ncol < HID)
          dst[(size_t)m * HID + ncol] = acc[fm][fn][j];
      }
    }
  }
}

// ---------------- reduce 8 partials + bias + relu -> h bf16 [320][4096] ----------------
__global__ void reduce_k(const float* __restrict__ part,
                         const float* __restrict__ b1,
                         unsigned short* __restrict__ hb) {
  int n = blockIdx.x * 256 + threadIdx.x;
  int p = blockIdx.y;
  if (n >= K2PAD) return;
  float v = 0.0f;
  if (n < HID) {
    size_t i = (size_t)p * HID + n;
    const size_t S = (size_t)NP * HID;
    float s0 = 0.f;
    #pragma unroll
    for (int k = 0; k < KSPLIT1; ++k) s0 += part[i + (size_t)k*S];
    v = fmaxf(s0 + b1[n], 0.0f);
  }
  hb[(size_t)p * K2PAD + n] = f2bf(v);
}

// ---------------- GEMM2 (MFMA split-K): hb[320][4096] x [Wc|Wr|0][4096][128] -> part2 ----------------
__global__ __launch_bounds__(512, 1)
void gemm2_k(const unsigned short* __restrict__ hb,
             const float* __restrict__ Wc,
             const float* __restrict__ Wr,
             float* __restrict__ part2) {
  __shared__ char lds[2*BUFBYTES];
  const int t = threadIdx.x;
  const int wave = t >> 6;
  const int lane = t & 63;
  const int ntile = blockIdx.x;
  const int kc = blockIdx.y;
  const int n0 = ntile * BN;
  const int kstart0 = kc * KC2;

  const int bn_l = t & 63;
  const int bk8  = (t >> 6) * 8;
  const int jn   = n0 + bn_l;
  const float* bsrc; int bst;
  if (jn < 21)        { bsrc = Wc + jn;        bst = 21; }
  else if (jn < 101)  { bsrc = Wr + (jn - 21); bst = 80; }
  else                { bsrc = nullptr;        bst = 0;  }
  const int bwoff = ABYTES + bn_l*128 + ((bk8*2) ^ ((bn_l & 7) << 4));

  const int wm = wave >> 1;
  const int wn = wave & 1;

  int aoff[5][2], boff[2][2];
  #pragma unroll
  for (int fm = 0; fm < 5; ++fm) {
    int row = wm*80 + fm*16 + (lane & 15);
    #pragma unroll
    for (int h = 0; h < 2; ++h) {
      int kb = (h << 6) | ((lane >> 4) << 4);
      aoff[fm][h] = row*128 + (kb ^ ((row & 7) << 4));
    }
  }
  #pragma unroll
  for (int fn = 0; fn < 2; ++fn) {
    int col = wn*32 + fn*16 + (lane & 15);
    #pragma unroll
    for (int h = 0; h < 2; ++h) {
      int kb = (h << 6) | ((lane >> 4) << 4);
      boff[fn][h] = ABYTES + col*128 + (kb ^ ((col & 7) << 4));
    }
  }

  f32x4 acc[5][2];
  #pragma unroll
  for (int fm=0; fm<5; ++fm)
    #pragma unroll
    for (int fn=0; fn<2; ++fn)
      acc[fm][fn] = (f32x4){0.f,0.f,0.f,0.f};

  auto stageA = [&](int s, int buf) {
    const int kstart = kstart0 + s*BK;
    char* dstbase = lds + buf*BUFBYTES;
    #pragma unroll
    for (int i = 0; i < 5; ++i) {
      int chunk = wave*5 + i;
      int o = chunk*1024 + lane*16;
      int row = o >> 7;
      int kb = (o & 127) ^ ((row & 7) << 4);
      const char* g = (const char*)hb + (size_t)row*(K2PAD*2) + (size_t)kstart*2 + kb;
      __builtin_amdgcn_global_load_lds(
          (const __attribute__((address_space(1))) unsigned int*)g,
          (__attribute__((address_space(3))) unsigned int*)(dstbase + chunk*1024),
          16, 0, 0);
    }
  };
  auto loadB = [&](int s, float* bv) {
    const int kstart = kstart0 + s*BK;
    #pragma unroll
    for (int i = 0; i < 8; ++i) {
      int k = kstart + bk8 + i;
      bv[i] = (bsrc && k < HID) ? bsrc[(size_t)k * bst] : 0.0f;
    }
  };
  auto writeB = [&](const float* bv, int buf) {
    bf16x8 bb;
    #pragma unroll
    for (int i = 0; i < 8; ++i) bb[i] = (short)f2bf(bv[i]);
    *(bf16x8*)(lds + buf*BUFBYTES + bwoff) = bb;
  };
  auto compute = [&](int buf) {
    const char* base = lds + buf*BUFBYTES;
    #pragma unroll
    for (int h = 0; h < 2; ++h) {
      bf16x8 af[5], bfr[2];
      #pragma unroll
      for (int fm = 0; fm < 5; ++fm) af[fm] = *(const bf16x8*)(base + aoff[fm][h]);
      #pragma unroll
      for (int fn = 0; fn < 2; ++fn) bfr[fn] = *(const bf16x8*)(base + boff[fn][h]);
      #pragma unroll
      for (int fm = 0; fm < 5; ++fm)
        #pragma unroll
        for (int fn = 0; fn < 2; ++fn)
          acc[fm][fn] = __builtin_amdgcn_mfma_f32_16x16x32_bf16(af[fm], bfr[fn], acc[fm][fn], 0, 0, 0);
    }
  };

  {
    float bv[8];
    loadB(0, bv);
    stageA(0, 0);
    writeB(bv, 0);
  }
  __syncthreads();

  for (int s = 0; s < NSTEP2; ++s) {
    int cur = s & 1;
    float bv[8];
    if (s + 1 < NSTEP2) {
      loadB(s+1, bv);
      stageA(s+1, cur^1);
    }
    compute(cur);
    if (s + 1 < NSTEP2) {
      writeB(bv, cur^1);
    }
    __syncthreads();
  }

  float* dst = part2 + (size_t)kc * PM * 128;
  #pragma unroll
  for (int fm = 0; fm < 5; ++fm) {
    #pragma unroll
    for (int fn = 0; fn < 2; ++fn) {
      int ncol = n0 + wn*32 + fn*16 + (lane & 15);
      #pragma unroll
      for (int j = 0; j < 4; ++j) {
        int m = wm*80 + fm*16 + ((lane >> 4) * 4) + j;
        dst[(size_t)m * 128 + ncol] = acc[fm][fn][j];
      }
    }
  }
}

// ---------------- reduce2: sum K-slices + bias -> out ----------------
__global__ void reduce2_k(const float* __restrict__ part2,
                          const float* __restrict__ bc,
                          const float* __restrict__ br,
                          float* __restrict__ out) {
  int p = blockIdx.x;
  int j = threadIdx.x;
  if (j >= 101) return;
  float s = 0.0f;
  #pragma unroll 8
  for (int k = 0; k < KSL; ++k)
    s += part2[(size_t)k * PM * 128 + (size_t)p * 128 + j];
  if (j < 21) out[(size_t)p*21 + j] = s + bc[j];
  else        out[6300 + (size_t)p*80 + (j-21)] = s + br[j-21];
}

extern "C" void kernel_launch(void* const* d_in, const int* in_sizes, int n_in,
                              void* d_out, int out_size, void* d_ws, size_t ws_size,
                              hipStream_t stream) {
  const float* fmap  = (const float*)d_in[0];
  const float* props = (const float*)d_in[1];
  const float* W1    = (const float*)d_in[2];
  const float* b1    = (const float*)d_in[3];
  const float* Wc    = (const float*)d_in[4];
  const float* bc    = (const float*)d_in[5];
  const float* Wr    = (const float*)d_in[6];
  const float* br    = (const float*)d_in[7];
  float* out = (float*)d_out;
  char* ws = (char*)d_ws;

  unsigned short* pooled = (unsigned short*)ws;                     // 16,056,320 B
  float* part = (float*)(ws + 16056320);                            // 8*300*4069*4 = 39,062,400 B
  unsigned short* hb = (unsigned short*)(ws + 16056320 + 39062400); //  2,621,440 B
  float* part2 = (float*)(ws + 16056320 + 39062400 + 2621440);      //  5,242,880 B

  roi_pool_k<<<PM, 256, 0, stream>>>(fmap, props, pooled);
  gemm1_k<<<256, 512, 0, stream>>>(pooled, W1, part);
  reduce_k<<<dim3(K2PAD/256, NP), 256, 0, stream>>>(part, b1, hb);
  gemm2_k<<<dim3(2, KSL), 512, 0, stream>>>(hb, Wc, Wr, part2);
  reduce2_k<<<NP, 128, 0, stream>>>(part2, bc, br, out);
}